// Round 6
// baseline (159.087 us; speedup 1.0000x reference)
//
#include <hip/hip_runtime.h>
#include <hip/hip_bf16.h>

#define B_   4
#define S_   4096
#define DIN  768
#define DH   64

typedef float f32x4 __attribute__((ext_vector_type(4)));
typedef short s16x8 __attribute__((ext_vector_type(8)));
typedef int   i32x4 __attribute__((ext_vector_type(4)));
typedef unsigned short u16;

__device__ __forceinline__ u16 f2bf(float f) {
  union { float f; unsigned int u; } a; a.f = f;
  unsigned int u = a.u;
  unsigned int r = (u + 0x7fffu + ((u >> 16) & 1u)) >> 16;  // RNE
  return (u16)r;
}

// pack two floats to bf16 pair (round-half-up) -> u32
__device__ __forceinline__ unsigned int bfpack2(float a, float b) {
  union { float f; unsigned int u; } ua, ub; ua.f = a; ub.f = b;
  return ((ua.u + 0x8000u) >> 16) | ((ub.u + 0x8000u) & 0xffff0000u);
}

__device__ __forceinline__ s16x8 ld8s(const u16* p) {
  return *reinterpret_cast<const s16x8*>(p);
}

// fast pack of 8 fp32 -> bf16x8 (round-half-up)
__device__ __forceinline__ s16x8 pack8f(float4 a, float4 b) {
  union { i32x4 i; s16x8 s; } u;
  u.i[0] = (int)bfpack2(a.x, a.y);
  u.i[1] = (int)bfpack2(a.z, a.w);
  u.i[2] = (int)bfpack2(b.x, b.y);
  u.i[3] = (int)bfpack2(b.z, b.w);
  return u.s;
}

#define GLD_LDS(gp, lp) \
  __builtin_amdgcn_global_load_lds((const __attribute__((address_space(1))) void*)(gp), \
                                   (__attribute__((address_space(3))) void*)(lp), 16, 0, 0)

// ---------------- kernel 0: W transpose + bf16 + swizzle (LDS transpose) ------
// 36 blocks: mtx = bid/12 (wq/wk/wv), k0 = (bid%12)*64. Coalesced read + write.
__global__ __launch_bounds__(256) void prep_w(const float* __restrict__ wq,
    const float* __restrict__ wk, const float* __restrict__ wv, u16* __restrict__ wt) {
  __shared__ u16 tl[64 * 65];
  int bid = blockIdx.x;
  int mtx = bid / 12;
  int k0 = (bid % 12) * 64;
  const float* src = (mtx == 0) ? wq : (mtx == 1) ? wk : wv;
  float scale = (mtx == 0) ? 0.125f : 1.0f;
  int t = threadIdx.x;
  int rr = t >> 6, cc = t & 63;
#pragma unroll
  for (int i = 0; i < 16; i++) {
    int kr = i * 4 + rr;
    tl[kr * 65 + cc] = f2bf(src[(size_t)(k0 + kr) * 64 + cc] * scale);
  }
  __syncthreads();
  int nbase = mtx * 64;
#pragma unroll
  for (int i = 0; i < 16; i++) {
    int nl = i * 4 + rr;
    int n = nbase + nl;
    int gr = (cc >> 3) ^ (n & 7);
    wt[(size_t)n * DIN + k0 + gr * 8 + (cc & 7)] = tl[cc * 65 + nl];
  }
}

// ---------------- kernel 1: QKV projection GEMM (x direct to registers) -------
// 512 blocks of 256 thr (4 waves). Block = 32 rows, all 192 cols.
// Wave (wr,wc): rows 16*wr+lq, cols 96*wc.. ; x in 24 A-frags; W dbuf in LDS.
__global__ __launch_bounds__(256, 3) void qkv_gemm(const float* __restrict__ x,
    const u16* __restrict__ wt, u16* __restrict__ qb, u16* __restrict__ kb,
    u16* __restrict__ vt) {
  __shared__ __align__(16) u16 wl[2][192 * 64];
  int t = threadIdx.x;
  int w = t >> 6, l = t & 63, g = l >> 4, lq = l & 15;
  int wr = w >> 1, wc = w & 1;
  int m0 = blockIdx.x * 32;

  // issue W tile 0 staging first
#pragma unroll
  for (int i = 0; i < 6; i++) {
    int tau = i * 4 + w; int n = 8 * tau + (l >> 3);
    GLD_LDS(wt + n * DIN + (l & 7) * 8, &wl[0][tau * 512]);
  }

  // x -> 24 A-fragments (full K=768) for row m0 + 16*wr + lq, k-slice g*8
  const float* xrowp = x + (size_t)(m0 + 16 * wr + lq) * DIN + g * 8;
  s16x8 af[24];
#pragma unroll
  for (int c = 0; c < 24; c++) {
    float4 a = *reinterpret_cast<const float4*>(xrowp + c * 32);
    float4 b = *reinterpret_cast<const float4*>(xrowp + c * 32 + 4);
    af[c] = pack8f(a, b);
  }

  f32x4 acc[6];
#pragma unroll
  for (int i = 0; i < 6; i++) acc[i] = f32x4{0.f, 0.f, 0.f, 0.f};

  asm volatile("s_waitcnt vmcnt(0)" ::: "memory");
  __syncthreads();

#pragma unroll
  for (int ks = 0; ks < 12; ks++) {
    int cur = ks & 1;
    if (ks < 11) {
      int k1 = (ks + 1) * 64;
#pragma unroll
      for (int i = 0; i < 6; i++) {
        int tau = i * 4 + w; int n = 8 * tau + (l >> 3);
        GLD_LDS(wt + n * DIN + k1 + (l & 7) * 8, &wl[cur ^ 1][tau * 512]);
      }
    }
#pragma unroll
    for (int nt = 0; nt < 6; nt++) {
      int n = wc * 96 + nt * 16 + lq;
      s16x8 b0 = ld8s(&wl[cur][n * 64 + ((g ^ (n & 7)) * 8)]);
      s16x8 b1 = ld8s(&wl[cur][n * 64 + (((g + 4) ^ (n & 7)) * 8)]);
      acc[nt] = __builtin_amdgcn_mfma_f32_16x16x32_bf16(af[2 * ks], b0, acc[nt], 0, 0, 0);
      acc[nt] = __builtin_amdgcn_mfma_f32_16x16x32_bf16(af[2 * ks + 1], b1, acc[nt], 0, 0, 0);
    }
    if (ks < 11) {
      asm volatile("s_waitcnt vmcnt(0)" ::: "memory");
      __syncthreads();
    }
  }

  // epilogue
  int b = m0 >> 12;
  int srow0 = (m0 & (S_ - 1)) + 16 * wr + 4 * g;
#pragma unroll
  for (int nt = 0; nt < 6; nt++) {
    int col = wc * 96 + nt * 16 + lq;
    u16* base; int c;
    if (col < 64)       { base = qb; c = col; }
    else if (col < 128) { base = kb; c = col - 64; }
    else                { base = vt; c = col - 128; }
#pragma unroll
    for (int r = 0; r < 4; r++) {
      int srow = srow0 + r;
      u16 hv = f2bf(acc[nt][r]);
      if (col < 128) {
        int gr = (c >> 3) ^ (srow & 7);
        base[(size_t)(b * S_ + srow) * DH + gr * 8 + (c & 7)] = hv;
      } else {
        int gr = ((srow >> 3) & 7) ^ (c & 7);
        base[(size_t)(b * DH + c) * S_ + (srow & ~63) + gr * 8 + (srow & 7)] = hv;
      }
    }
  }
}

// ---------------- kernel 2: flash attention (in-register P redistribution) ----
// 256 blocks of 512 thr (8 waves). Waves 0-3: kv half 0, waves 4-7: half 1.
// LDS 64KB -> 2 blocks/CU. P never touches LDS: bpermute within lane columns.
__global__ __launch_bounds__(512, 4) void attn(const u16* __restrict__ qb,
    const u16* __restrict__ kb, const u16* __restrict__ vt, float* __restrict__ out) {
  __shared__ __align__(16) u16 smem[32768];   // 64KB: staging only

  int t = threadIdx.x;
  int w8 = t >> 6, half = w8 >> 2, w = w8 & 3, l = t & 63, g = l >> 4, lq = l & 15;
  int bq = blockIdx.x;
  int b = bq >> 6;
  int q0 = (bq & 63) * 64;
  int kvbase = half * 2048;

  // Q fragments (pre-scaled by 0.125 in projection)
  int sq = q0 + 16 * w + lq;
  const u16* qrow = qb + (size_t)(b * S_ + sq) * DH;
  s16x8 qa0 = ld8s(qrow + ((g ^ (sq & 7)) * 8));
  s16x8 qa1 = ld8s(qrow + (((g + 4) ^ (sq & 7)) * 8));

  // bpermute byte-indices for P redistribution (fixed per lane)
  int sA = ((2 * (g & 1)) << 4) | lq;
  int idxA = sA << 2;
  int idxB = idxA + 64;          // lane sA+16
  bool chi = ((g >> 1) & 1);     // kt-select within pair

  float mrun = -1e30f, lrun = 0.f;
  f32x4 acco[4];
#pragma unroll
  for (int nt = 0; nt < 4; nt++) acco[nt] = f32x4{0.f, 0.f, 0.f, 0.f};

  int tau0 = w * 2;
  int srow_st = 8 * tau0 + (l >> 3);
  int gcol = (l & 7) * 8;

  // prologue: stage tile 0 into buf 0
  {
    u16* dst = smem + half * 16384;
#pragma unroll
    for (int i = 0; i < 2; i++) {
      int row = srow_st + 8 * i;
      GLD_LDS(kb + (size_t)(b * S_ + kvbase + row) * DH + gcol, &dst[(tau0 + i) * 512]);
      GLD_LDS(vt + (size_t)(b * DH + row) * S_ + kvbase + gcol, &dst[4096 + (tau0 + i) * 512]);
    }
    asm volatile("s_waitcnt vmcnt(0)" ::: "memory");
    __syncthreads();
  }

  const float L2E = 1.44269504f;

  for (int it = 0; it < 32; it++) {
    int cur = it & 1;
    bool more = it < 31;
    if (more) {
      int k1 = kvbase + (it + 1) * 64;
      u16* dst = smem + half * 16384 + (cur ^ 1) * 8192;
#pragma unroll
      for (int i = 0; i < 2; i++) {
        int row = srow_st + 8 * i;
        GLD_LDS(kb + (size_t)(b * S_ + k1 + row) * DH + gcol, &dst[(tau0 + i) * 512]);
        GLD_LDS(vt + (size_t)(b * DH + row) * S_ + k1 + gcol, &dst[4096 + (tau0 + i) * 512]);
      }
    }
    const u16* kl = smem + half * 16384 + cur * 8192;
    const u16* vl = kl + 4096;

    // S^T = K Q^T : lane (g,lq) holds S[k=16kt+4g+r][q=lq]
    f32x4 accs[4];
#pragma unroll
    for (int kt = 0; kt < 4; kt++) {
      int krow = kt * 16 + lq;
      s16x8 kf0 = ld8s(&kl[krow * 64 + ((g ^ (krow & 7)) * 8)]);
      s16x8 kf1 = ld8s(&kl[krow * 64 + (((g + 4) ^ (krow & 7)) * 8)]);
      f32x4 c = f32x4{0.f, 0.f, 0.f, 0.f};
      c = __builtin_amdgcn_mfma_f32_16x16x32_bf16(kf0, qa0, c, 0, 0, 0);
      c = __builtin_amdgcn_mfma_f32_16x16x32_bf16(kf1, qa1, c, 0, 0, 0);
      accs[kt] = c;
    }

    // lane-local softmax for q = lq (column group reduce over 4 g-copies)
    f32x4 m4 = accs[0];
#pragma unroll
    for (int kt = 1; kt < 4; kt++) {
      m4[0] = fmaxf(m4[0], accs[kt][0]); m4[1] = fmaxf(m4[1], accs[kt][1]);
      m4[2] = fmaxf(m4[2], accs[kt][2]); m4[3] = fmaxf(m4[3], accs[kt][3]);
    }
    float mx = fmaxf(fmaxf(m4[0], m4[1]), fmaxf(m4[2], m4[3]));
    mx = fmaxf(mx, __shfl_xor(mx, 16));
    mx = fmaxf(mx, __shfl_xor(mx, 32));
    float mnew = fmaxf(mrun, mx);
    float scale = exp2f((mrun - mnew) * L2E);
    float sc0 = __shfl(scale, 4 * g + 0);
    float sc1 = __shfl(scale, 4 * g + 1);
    float sc2 = __shfl(scale, 4 * g + 2);
    float sc3 = __shfl(scale, 4 * g + 3);

    float s = 0.f;
#pragma unroll
    for (int kt = 0; kt < 4; kt++) {
#pragma unroll
      for (int r = 0; r < 4; r++) {
        float e = exp2f((accs[kt][r] - mnew) * L2E);
        accs[kt][r] = e; s += e;
      }
    }
    s += __shfl_xor(s, 16);
    s += __shfl_xor(s, 32);
    lrun = lrun * scale + s;
    mrun = mnew;

    // pack P to bf16 pairs: pk[kt*2+h] covers k = 16kt + 4g + 2h + {0,1}
    int pk0 = (int)bfpack2(accs[0][0], accs[0][1]);
    int pk1 = (int)bfpack2(accs[0][2], accs[0][3]);
    int pk2 = (int)bfpack2(accs[1][0], accs[1][1]);
    int pk3 = (int)bfpack2(accs[1][2], accs[1][3]);
    int pk4 = (int)bfpack2(accs[2][0], accs[2][1]);
    int pk5 = (int)bfpack2(accs[2][2], accs[2][3]);
    int pk6 = (int)bfpack2(accs[3][0], accs[3][1]);
    int pk7 = (int)bfpack2(accs[3][2], accs[3][3]);

    // redistribute to PV A-frag layout: lane needs k = 8g..8g+7 (pa0), 32+8g.. (pa1)
    int fA0 = __builtin_amdgcn_ds_bpermute(idxA, pk0);
    int fA1 = __builtin_amdgcn_ds_bpermute(idxA, pk1);
    int fA2 = __builtin_amdgcn_ds_bpermute(idxA, pk2);
    int fA3 = __builtin_amdgcn_ds_bpermute(idxA, pk3);
    int fA4 = __builtin_amdgcn_ds_bpermute(idxA, pk4);
    int fA5 = __builtin_amdgcn_ds_bpermute(idxA, pk5);
    int fA6 = __builtin_amdgcn_ds_bpermute(idxA, pk6);
    int fA7 = __builtin_amdgcn_ds_bpermute(idxA, pk7);
    int fB0 = __builtin_amdgcn_ds_bpermute(idxB, pk0);
    int fB1 = __builtin_amdgcn_ds_bpermute(idxB, pk1);
    int fB2 = __builtin_amdgcn_ds_bpermute(idxB, pk2);
    int fB3 = __builtin_amdgcn_ds_bpermute(idxB, pk3);
    int fB4 = __builtin_amdgcn_ds_bpermute(idxB, pk4);
    int fB5 = __builtin_amdgcn_ds_bpermute(idxB, pk5);
    int fB6 = __builtin_amdgcn_ds_bpermute(idxB, pk6);
    int fB7 = __builtin_amdgcn_ds_bpermute(idxB, pk7);

    union { i32x4 i; s16x8 h; } upa0, upa1;
    upa0.i[0] = chi ? fA2 : fA0;  upa0.i[1] = chi ? fA3 : fA1;
    upa0.i[2] = chi ? fB2 : fB0;  upa0.i[3] = chi ? fB3 : fB1;
    upa1.i[0] = chi ? fA6 : fA4;  upa1.i[1] = chi ? fA7 : fA5;
    upa1.i[2] = chi ? fB6 : fB4;  upa1.i[3] = chi ? fB7 : fB5;

    // rescale O accumulator (row q = 4g+r)
#pragma unroll
    for (int nt = 0; nt < 4; nt++) {
      acco[nt][0] *= sc0; acco[nt][1] *= sc1;
      acco[nt][2] *= sc2; acco[nt][3] *= sc3;
    }

#pragma unroll
    for (int nt = 0; nt < 4; nt++) {
      int d = nt * 16 + lq;
      s16x8 vf0 = ld8s(&vl[d * 64 + ((g ^ (d & 7)) * 8)]);
      s16x8 vf1 = ld8s(&vl[d * 64 + (((g + 4) ^ (d & 7)) * 8)]);
      acco[nt] = __builtin_amdgcn_mfma_f32_16x16x32_bf16(upa0.h, vf0, acco[nt], 0, 0, 0);
      acco[nt] = __builtin_amdgcn_mfma_f32_16x16x32_bf16(upa1.h, vf1, acco[nt], 0, 0, 0);
    }
    if (more) {
      asm volatile("s_waitcnt vmcnt(0)" ::: "memory");
      __syncthreads();
    }
  }

  // ---- merge the two kv halves ----
  __syncthreads();
  float* mO = reinterpret_cast<float*>(smem);          // 64*64 f32 (16KB)
  float* mM = reinterpret_cast<float*>(smem) + 4096;   // 64
  float* mL = mM + 64;                                 // 64

  if (half == 1) {
#pragma unroll
    for (int nt = 0; nt < 4; nt++)
#pragma unroll
      for (int r = 0; r < 4; r++)
        mO[(16 * w + 4 * g + r) * 64 + nt * 16 + lq] = acco[nt][r];
    if (g == 0) {
      mM[16 * w + lq] = mrun;
      mL[16 * w + lq] = lrun;
    }
  }
  __syncthreads();
  if (half == 0) {
#pragma unroll
    for (int r = 0; r < 4; r++) {
      int row = 16 * w + 4 * g + r;
      float m1 = __shfl(mrun, 4 * g + r);
      float l1 = __shfl(lrun, 4 * g + r);
      float m2 = mM[row], l2 = mL[row];
      float m = fmaxf(m1, m2);
      float f1 = exp2f((m1 - m) * 1.44269504f);
      float f2 = exp2f((m2 - m) * 1.44269504f);
      float inv = 1.0f / (l1 * f1 + l2 * f2);
#pragma unroll
      for (int nt = 0; nt < 4; nt++) {
        float val = (acco[nt][r] * f1 + mO[row * 64 + nt * 16 + lq] * f2) * inv;
        out[(size_t)(b * S_ + q0 + row) * DH + nt * 16 + lq] = val;
      }
    }
  }
}

extern "C" void kernel_launch(void* const* d_in, const int* in_sizes, int n_in,
                              void* d_out, int out_size, void* d_ws, size_t ws_size,
                              hipStream_t stream) {
  const float* x  = (const float*)d_in[0];
  const float* wq = (const float*)d_in[1];
  const float* wk = (const float*)d_in[2];
  const float* wv = (const float*)d_in[3];
  float* out = (float*)d_out;
  char* ws = (char*)d_ws;

  u16* wt = (u16*)(ws);
  u16* qb = (u16*)(ws + 294912);
  u16* kb = (u16*)(ws + 294912 + 2097152);
  u16* vt = (u16*)(ws + 294912 + 2 * 2097152);

  hipLaunchKernelGGL(prep_w,   dim3(36),  dim3(256), 0, stream, wq, wk, wv, wt);
  hipLaunchKernelGGL(qkv_gemm, dim3(512), dim3(256), 0, stream, x, wt, qb, kb, vt);
  hipLaunchKernelGGL(attn,     dim3(256), dim3(512), 0, stream, qb, kb, vt, out);
}